// Round 24
// baseline (49.919 us; speedup 1.0000x reference)
//
#include <hip/hip_runtime.h>
#include <math.h>

// NonlocalWeightedAverage via MX-scaled fp8 MFMA (K=64), fixed-reference
// softmax. corr[m,n] = <lf_m, lf_n>, lf = 3x3-unfolded feature, K = 9*64.
// R24: WAVE-PRIVATE window rings -> BARRIER-FREE main loop. Each wave reads
// only stripes {h,2+h} x window xx [nh*32-1, nh*32+32]; private slab =
// 4 stripes x 34 pos x 16B = 2176B; 6-slot ring/wave (104.4KB for 8 waves).
// Staging is per-wave (glds16, 33 active lanes per stripe) -> no cross-wave
// hazards -> no __syncthreads in the loop; sync = s_waitcnt vmcnt(0) at
// sub-SP start (drains prev sub-SP's stages; ~free, latency covered by one
// sub-SP). Storage pos p = l31+dx for BOTH sides (nh/mt); 1 pad chunk per
// stripe pre-zeroed. R21-23 showed pipe-work reductions are neutral: the
// wall is dependency bubbles in lockstep waves; this decouples them.

#define B_ 4
#define CH 64
#define H_ 64
#define W_ 64
#define SCALE2 14.426950408889634f   // (1/ALPHA=10) * log2(e)
#define SLOT 2176                    // 4 stripes * 34 pos * 16B
#define NRING 6
#define WRING (NRING * SLOT)         // 13056 B per wave

typedef __attribute__((ext_vector_type(4)))  unsigned int uint4v;
typedef __attribute__((ext_vector_type(16))) float f32x16;
typedef __attribute__((ext_vector_type(8)))  int int8v;

__device__ inline void glds16(const void* g, void* l) {
    __builtin_amdgcn_global_load_lds(
        (const __attribute__((address_space(1))) unsigned int*)g,
        (__attribute__((address_space(3))) unsigned int*)l, 16, 0, 0);
}

// decode OCP e4m3fn (NaN never occurs for our data: |f| <= ~5 << 448)
__device__ inline float dec_e4m3(unsigned u) {
    unsigned e = (u >> 3) & 15u, m = u & 7u;
    float v = e ? __uint_as_float(((e + 120u) << 23) | (m << 20))
                : (float)m * 0x1p-9f;
    return (u & 0x80u) ? -v : v;
}

// feat [B,C,H,W] f32 -> tf [B,H,W,64] fp8 e4m3 (fragment-pair packed), plus
// per-pixel channel-norm^2 of the DECODED fp8 values -> n2 [B,H,W].
__global__ __launch_bounds__(256) void feat_to_fp8(
    const float* __restrict__ feat, unsigned char* __restrict__ tf,
    float* __restrict__ n2)
{
    const int b = blockIdx.y, y = blockIdx.x, t = (int)threadIdx.x;
    __shared__ float ld[CH][W_ + 1];
    #pragma unroll
    for (int i = 0; i < 16; ++i) {
        int idx = i * 256 + t;
        int c = idx >> 6, x = idx & 63;
        ld[c][x] = feat[(((size_t)b * CH + c) * H_ + y) * W_ + x];
    }
    __syncthreads();
    const int x = t >> 2, g = t & 3;
    const int cbase = (g >> 1) * 32 + (g & 1) * 8;
    unsigned int wd[4];
    #pragma unroll
    for (int w4 = 0; w4 < 4; ++w4) {
        float f[4];
        #pragma unroll
        for (int e = 0; e < 4; ++e) {
            int j = w4 * 4 + e;
            f[e] = ld[cbase + ((j >> 3) << 4) + (j & 7)][x];
        }
        unsigned int wv = 0;
        wv = __builtin_amdgcn_cvt_pk_fp8_f32(f[0], f[1], wv, false);
        wv = __builtin_amdgcn_cvt_pk_fp8_f32(f[2], f[3], wv, true);
        wd[w4] = wv;
    }
    float s = 0.f;
    #pragma unroll
    for (int w4 = 0; w4 < 4; ++w4)
        #pragma unroll
        for (int e = 0; e < 4; ++e) {
            float d = dec_e4m3((wd[w4] >> (8 * e)) & 0xffu);
            s = fmaf(d, d, s);
        }
    s += __shfl_xor(s, 1);
    s += __shfl_xor(s, 2);
    if (g == 0) n2[((size_t)b * H_ + y) * W_ + x] = s;

    unsigned char* dst = tf + (((size_t)b * H_ + y) * W_ + x) * CH + g * 16;
    *(uint4v*)dst = (uint4v){wd[0], wd[1], wd[2], wd[3]};
}

#define MXMFMA(A, Bv, C) \
    __builtin_amdgcn_mfma_scale_f32_32x32x64_f8f6f4(A, Bv, C, 0, 0, 0, 0x7F, 0, 0x7F)

__global__ __launch_bounds__(512) void nlwa_fp8(
    const float* __restrict__ xlab,
    const unsigned char* __restrict__ tf,
    const float* __restrict__ n2,
    float* __restrict__ out)
{
    const int b = blockIdx.y, ym = blockIdx.x;
    const int tid = (int)threadIdx.x;
    const int w = tid >> 6, l = tid & 63;   // EIGHT waves
    const int l31 = l & 31, h = l >> 5;
    const int zh = w >> 2;            // yn-half: [0,32) or [32,64)
    const int mt = (w >> 1) & 1, nh = w & 1;
    const int lo = zh << 5;

    __shared__ __attribute__((aligned(16))) char smem[8 * WRING]; // 104448 B
    __shared__ float state[2][2][64][4];  // [zh][nh][m]{S,W0,W1,pad}
    __shared__ float mref_lds[64];
    char* wring = smem + w * WRING;       // this wave's private 6-slot ring

    const unsigned char* tfb = tf + (size_t)b * H_ * W_ * CH;
    const float* aab = xlab + ((size_t)b * 3 + 1) * H_ * W_;
    const float* bab = xlab + ((size_t)b * 3 + 2) * H_ * W_;

    // zero softmax state (1024 floats over 512 threads)
    #pragma unroll
    for (int i = 0; i < 2; ++i) ((float*)state)[i * 512 + tid] = 0.f;

    // Mref[x] = SCALE2 * 3x3 box-sum of n2 around (ym, x), zero-padded
    if (tid < 64) {
        const float* n2b = n2 + (size_t)b * H_ * W_;
        float s = 0.f;
        #pragma unroll
        for (int dy = -1; dy <= 1; ++dy) {
            int y = ym + dy;
            if ((unsigned)y < H_) {
                #pragma unroll
                for (int dx = -1; dx <= 1; ++dx) {
                    int x = tid + dx;
                    if ((unsigned)x < W_) s += n2b[y * W_ + x];
                }
            }
        }
        mref_lds[tid] = s * SCALE2;
    }

    // per-wave: zero BOTH pad candidates (pos 0 and 33) of all slots/stripes
    if (l < 48) {
        int slot = l >> 3, s = (l >> 1) & 3, e = l & 1;
        *(uint4v*)(wring + slot * SLOT + (s * 34 + (e ? 33 : 0)) * 16) =
            (uint4v){0, 0, 0, 0};
    }

    // stage stripe s of row y into slot (window of `side`): valid pixels
    // x = side*31 + j (j=0..32) at storage pos j + (1-side). OOB row -> zeros.
    auto stage_w = [&](char* slotp, int y, int s, int side) {
        char* dstb = slotp + (s * 34 + 1 - side) * 16;
        if ((unsigned)y < H_) {
            if (l < 33)
                glds16(tfb + ((size_t)y * W_ + side * 31 + l) * CH + s * 16, dstb);
        } else {
            if (l < 33) *(uint4v*)(dstb + l * 16) = (uint4v){0, 0, 0, 0};
        }
    };

    // read the 32B MX operand at dx from a slot: pos p = l31+dx (both sides),
    // stripes {h, 2+h}.
    const int pbL = (h * 34 + l31) * 16;
    const int pbH = ((2 + h) * 34 + l31) * 16;
    auto ld32w = [&](const char* slotp, int dx) -> int8v {
        uint4v r0 = *(const uint4v*)(slotp + pbL + dx * 16);
        uint4v r1 = *(const uint4v*)(slotp + pbH + dx * 16);
        int8v a;
        a[0] = r0[0]; a[1] = r0[1]; a[2] = r0[2]; a[3] = r0[3];
        a[4] = r1[0]; a[5] = r1[1]; a[6] = r1[2]; a[7] = r1[3];
        return a;
    };

    __syncthreads();   // state/mref visible to all (pads are wave-private)

    // ---- A-phase: rows ym-1..ym+1 via slot 5, one at a time, side=mt ----
    char* aslot = wring + 5 * SLOT;
    int8v Areg0[3], Areg1[3], Areg2[3];
    #pragma unroll
    for (int dyi = 0; dyi < 3; ++dyi) {
        int y = ym + dyi - 1;
        #pragma unroll
        for (int s = 0; s < 4; ++s) stage_w(aslot, y, s, mt);
        asm volatile("s_waitcnt vmcnt(0)" ::: "memory");
        #pragma unroll
        for (int dx = 0; dx < 3; ++dx) {
            int8v vA = ld32w(aslot, dx);
            if (dyi == 0) Areg0[dx] = vA;
            else if (dyi == 1) Areg1[dx] = vA;
            else Areg2[dx] = vA;
        }
        asm volatile("s_waitcnt lgkmcnt(0)" ::: "memory");  // reads done before
    }                                                       // next row's DMA
    // re-zero this wave's nh-side pad chunks of slot 5 (A may have dirtied)
    if (l < 4)
        *(uint4v*)(aslot + (l * 34 + (nh ? 33 : 0)) * 16) = (uint4v){0,0,0,0};

    float Mref[16];
    #pragma unroll
    for (int r = 0; r < 16; ++r)
        Mref[r] = mref_lds[(mt << 5) + (r & 3) + ((r >> 2) << 3) + (h << 2)];

    const int xn = (nh << 5) + l31;   // lane's n-column

    // ---- ring prologue: rows lo-1..lo+2, side=nh ----
    #pragma unroll
    for (int j = 0; j < 4; ++j) {
        int y = lo - 1 + j;
        char* slotp = wring + ((y + 6) % 6) * SLOT;
        #pragma unroll
        for (int s = 0; s < 4; ++s) stage_w(slotp, y, s, nh);
    }

    // ---- 16 sub-SPs, NO barriers ----
    #pragma unroll 1
    for (int sp = 0; sp < 16; ++sp) {
        const int yb = lo + (sp << 1);

        // drain previous sub-SP's stages (full sub-SP of latency cover)
        asm volatile("s_waitcnt vmcnt(0)" ::: "memory");

        // stage rows yb+3, yb+4 (slots (yb+3)%6,(yb+4)%6 -- disjoint from
        // this sub-SP's read slots (yb-1..yb+2)%6)
        if (yb + 3 <= lo + 32) {
            char* sp3 = wring + ((yb + 3) % 6) * SLOT;
            #pragma unroll
            for (int s = 0; s < 4; ++s) stage_w(sp3, yb + 3, s, nh);
        }
        if (yb + 4 <= lo + 32) {
            char* sp4 = wring + ((yb + 4) % 6) * SLOT;
            #pragma unroll
            for (int s = 0; s < 4; ++s) stage_w(sp4, yb + 4, s, nh);
        }

        const char* rs0 = wring + ((yb - 1 + 6) % 6) * SLOT;
        const char* rs1 = wring + ((yb     + 6) % 6) * SLOT;
        const char* rs2 = wring + ((yb + 1) % 6) * SLOT;
        const char* rs3 = wring + ((yb + 2) % 6) * SLOT;

        f32x16 acc0, acc1;
        #pragma unroll
        for (int r = 0; r < 16; ++r) { acc0[r] = 0.f; acc1[r] = 0.f; }

        #pragma unroll
        for (int dx = 0; dx < 3; ++dx) {
            int8v Bb0 = ld32w(rs0, dx);
            int8v Bb1 = ld32w(rs1, dx);
            int8v Bb2 = ld32w(rs2, dx);
            int8v Bb3 = ld32w(rs3, dx);
            acc0 = MXMFMA(Areg0[dx], Bb0, acc0);
            acc0 = MXMFMA(Areg1[dx], Bb1, acc0);
            acc0 = MXMFMA(Areg2[dx], Bb2, acc0);
            acc1 = MXMFMA(Areg0[dx], Bb1, acc1);
            acc1 = MXMFMA(Areg1[dx], Bb2, acc1);
            acc1 = MXMFMA(Areg2[dx], Bb3, acc1);
        }

        // fixed-reference softmax: guard-gated LDS accumulation (state slices
        // are per-wave disjoint -> race-free without barriers)
        #pragma unroll
        for (int j = 0; j < 2; ++j) {
            const f32x16& ac = (j == 0) ? acc0 : acc1;
            float v[16]; int upd = 0;
            #pragma unroll
            for (int r = 0; r < 16; ++r) {
                v[r] = fmaf(ac[r], SCALE2, -Mref[r]);
                upd |= (v[r] > -30.0f) ? 1 : 0;
            }
            if (__any(upd)) {
                const int yn = yb + j;
                float av = aab[yn * W_ + xn];
                float bv = bab[yn * W_ + xn];
                #pragma unroll
                for (int r = 0; r < 16; ++r) {
                    float pp  = exp2f(fminf(v[r], 80.0f));
                    float w0c = pp * av;
                    float w1c = pp * bv;
                    #pragma unroll
                    for (int off = 16; off >= 1; off >>= 1) {
                        pp  += __shfl_xor(pp,  off);
                        w0c += __shfl_xor(w0c, off);
                        w1c += __shfl_xor(w1c, off);
                    }
                    if (l31 == 0) {
                        int m = (mt << 5) + (r & 3) + ((r >> 2) << 3) + (h << 2);
                        float* st = &state[zh][nh][m][0];
                        st[0] += pp; st[1] += w0c; st[2] += w1c;
                    }
                }
            }
        }
    }

    __syncthreads();   // all waves' state complete

    // final: sum the 4 partial states, write output directly
    if (tid < 64) {
        float Ssum = 0.f, w0 = 0.f, w1 = 0.f;
        #pragma unroll
        for (int z2 = 0; z2 < 2; ++z2)
            #pragma unroll
            for (int n2i = 0; n2i < 2; ++n2i) {
                Ssum += state[z2][n2i][tid][0];
                w0   += state[z2][n2i][tid][1];
                w1   += state[z2][n2i][tid][2];
            }
        float inv = 1.0f / Ssum;
        out[(((size_t)b * 2 + 0) * H_ + ym) * W_ + tid] = w0 * inv;
        out[(((size_t)b * 2 + 1) * H_ + ym) * W_ + tid] = w1 * inv;
    }
}

extern "C" void kernel_launch(void* const* d_in, const int* in_sizes, int n_in,
                              void* d_out, int out_size, void* d_ws, size_t ws_size,
                              hipStream_t stream) {
    const float* xlab = (const float*)d_in[0];
    const float* feat = (const float*)d_in[1];
    float* out = (float*)d_out;
    unsigned char* tf = (unsigned char*)d_ws;                          // 1 MB
    float* n2   = (float*)((char*)d_ws + (size_t)1024 * 1024);         // 64 KB

    dim3 gridT(H_, B_);
    feat_to_fp8<<<gridT, 256, 0, stream>>>(feat, tf, n2);
    dim3 gridM(H_, B_);
    nlwa_fp8<<<gridM, 512, 0, stream>>>(xlab, tf, n2, out);
}

// Round 25
// 43.126 us; speedup vs baseline: 1.1575x; 1.1575x over previous
//
#include <hip/hip_runtime.h>
#include <math.h>

// NonlocalWeightedAverage via MX-scaled fp8 MFMA (K=64), fixed-reference
// softmax. corr[m,n] = <lf_m, lf_n>, lf = 3x3-unfolded feature, K = 9*64.
// R25 = R21 verbatim (verified best: 43.2us total, 48.6us kernel).
// Structure: one 512-thread block per (b,ym); 8 waves = 2mt x 2nh x 2zh;
// per zh a 10-slot LDS ring of fp8 feature rows (stripe-packed, conflict-
// free); A-fragments hoisted to registers; 8 barrier periods each covering
// two 2-gen sub-superphases + 4-row async prefetch (global_load_lds);
// fixed-reference softmax (Mref = SCALE2*||lf_m||^2 from decoded fp8) with
// guard-gated rare-path accumulation into LDS state; direct output write.
// Post-R21 probes all failed: scheduling hints (R22 neutral), B-reg carry
// (R23 neutral), wave-private barrier-free rings (R24 -17%). Binding
// constraint: serial ds_read->MFMA->guard chain at 2 waves/SIMD (true regs
// ~160-192/wave incl. unified-file AGPRs; LDS 102KB -> 1 block/CU).

#define B_ 4
#define CH 64
#define H_ 64
#define W_ 64
#define SCALE2 14.426950408889634f   // (1/ALPHA=10) * log2(e)
#define STRIPE 1056                  // 66 xx * 16 B
#define ROWB (4 * STRIPE)            // 4224 B: one feature row (fp8)
#define NRING 10

typedef __attribute__((ext_vector_type(4)))  unsigned int uint4v;
typedef __attribute__((ext_vector_type(16))) float f32x16;
typedef __attribute__((ext_vector_type(8)))  int int8v;

__device__ inline void glds16(const void* g, void* l) {
    __builtin_amdgcn_global_load_lds(
        (const __attribute__((address_space(1))) unsigned int*)g,
        (__attribute__((address_space(3))) unsigned int*)l, 16, 0, 0);
}

// decode OCP e4m3fn (NaN never occurs for our data: |f| <= ~5 << 448)
__device__ inline float dec_e4m3(unsigned u) {
    unsigned e = (u >> 3) & 15u, m = u & 7u;
    float v = e ? __uint_as_float(((e + 120u) << 23) | (m << 20))
                : (float)m * 0x1p-9f;
    return (u & 0x80u) ? -v : v;
}

// feat [B,C,H,W] f32 -> tf [B,H,W,64] fp8 e4m3 (fragment-pair packed), plus
// per-pixel channel-norm^2 of the DECODED fp8 values -> n2 [B,H,W].
__global__ __launch_bounds__(256) void feat_to_fp8(
    const float* __restrict__ feat, unsigned char* __restrict__ tf,
    float* __restrict__ n2)
{
    const int b = blockIdx.y, y = blockIdx.x, t = (int)threadIdx.x;
    __shared__ float ld[CH][W_ + 1];
    #pragma unroll
    for (int i = 0; i < 16; ++i) {
        int idx = i * 256 + t;
        int c = idx >> 6, x = idx & 63;
        ld[c][x] = feat[(((size_t)b * CH + c) * H_ + y) * W_ + x];
    }
    __syncthreads();
    const int x = t >> 2, g = t & 3;
    const int cbase = (g >> 1) * 32 + (g & 1) * 8;
    unsigned int wd[4];
    #pragma unroll
    for (int w4 = 0; w4 < 4; ++w4) {
        float f[4];
        #pragma unroll
        for (int e = 0; e < 4; ++e) {
            int j = w4 * 4 + e;
            f[e] = ld[cbase + ((j >> 3) << 4) + (j & 7)][x];
        }
        unsigned int wv = 0;
        wv = __builtin_amdgcn_cvt_pk_fp8_f32(f[0], f[1], wv, false);
        wv = __builtin_amdgcn_cvt_pk_fp8_f32(f[2], f[3], wv, true);
        wd[w4] = wv;
    }
    float s = 0.f;
    #pragma unroll
    for (int w4 = 0; w4 < 4; ++w4)
        #pragma unroll
        for (int e = 0; e < 4; ++e) {
            float d = dec_e4m3((wd[w4] >> (8 * e)) & 0xffu);
            s = fmaf(d, d, s);
        }
    s += __shfl_xor(s, 1);
    s += __shfl_xor(s, 2);
    if (g == 0) n2[((size_t)b * H_ + y) * W_ + x] = s;

    unsigned char* dst = tf + (((size_t)b * H_ + y) * W_ + x) * CH + g * 16;
    *(uint4v*)dst = (uint4v){wd[0], wd[1], wd[2], wd[3]};
}

#define MXMFMA(A, Bv, C) \
    __builtin_amdgcn_mfma_scale_f32_32x32x64_f8f6f4(A, Bv, C, 0, 0, 0, 0x7F, 0, 0x7F)

__global__ __launch_bounds__(512) void nlwa_fp8(
    const float* __restrict__ xlab,
    const unsigned char* __restrict__ tf,
    const float* __restrict__ n2,
    float* __restrict__ out)
{
    const int b = blockIdx.y, ym = blockIdx.x;
    const int tid = (int)threadIdx.x;
    const int w = tid >> 6, l = tid & 63;   // EIGHT waves
    const int l31 = l & 31, h = l >> 5;
    const int zh = w >> 2;            // yn-half: [0,32) or [32,64)
    const int w4 = w & 3;             // wave-in-half
    const int mt = (w >> 1) & 1, nh = w & 1;
    const int lo = zh << 5;

    __shared__ __attribute__((aligned(16))) char smem[23 * ROWB]; // 2x10 ring + 3 A
    __shared__ float state[2][2][64][4];  // [zh][nh][m]{S,W0,W1,pad}
    __shared__ float mref_lds[64];
    char* ring  = smem + zh * (NRING * ROWB);
    char* aslab = smem + 2 * NRING * ROWB;

    const unsigned char* tfb = tf + (size_t)b * H_ * W_ * CH;
    const float* aab = xlab + ((size_t)b * 3 + 1) * H_ * W_;
    const float* bab = xlab + ((size_t)b * 3 + 2) * H_ * W_;

    // zero pad columns xx=0,65: 23 slabs x 4 stripes x 2 = 184 16B-chunks
    if (tid < 184) {
        int s23 = tid >> 3, rem = tid & 7;
        int which = rem >> 2, t = rem & 3;
        char* base = smem + s23 * ROWB;
        *(uint4v*)(base + t * STRIPE + (which ? 65 * 16 : 0)) = (uint4v){0,0,0,0};
    }
    // zero softmax state (1024 floats over 512 threads)
    #pragma unroll
    for (int i = 0; i < 2; ++i) ((float*)state)[i * 512 + tid] = 0.f;

    // Mref[x] = SCALE2 * 3x3 box-sum of n2 around (ym, x), zero-padded
    if (tid < 64) {
        const float* n2b = n2 + (size_t)b * H_ * W_;
        float s = 0.f;
        #pragma unroll
        for (int dy = -1; dy <= 1; ++dy) {
            int y = ym + dy;
            if ((unsigned)y < H_) {
                #pragma unroll
                for (int dx = -1; dx <= 1; ++dx) {
                    int x = tid + dx;
                    if ((unsigned)x < W_) s += n2b[y * W_ + x];
                }
            }
        }
        mref_lds[tid] = s * SCALE2;
    }

    // stage one (row y, stripe t): async DMA into xx=1..64 (1024 B), or zeros
    auto stage = [&](char* slabBase, int y, int t) {
        char* dst = slabBase + t * STRIPE + 16;
        if ((unsigned)y < H_) {
            const unsigned char* gp = tfb + ((size_t)y * W_ + l) * CH + t * 16;
            glds16(gp, dst);
        } else {
            *(uint4v*)(dst + l * 16) = (uint4v){0, 0, 0, 0};
        }
    };

    // prologue. zh0: ring rows lo-1..lo+4 (24 tasks) + A rows ym-1..ym+1
    // (12 tasks) = 36. zh1: ring rows lo-1..lo+4 (24).
    if (zh == 0) {
        for (int tau = w4; tau < 36; tau += 4) {
            int r = tau >> 2, t = tau & 3;
            if (r < 6) {
                int y = lo - 1 + r;
                stage(ring + ((y + 1) % NRING) * ROWB, y, t);
            } else {
                int dy = r - 6;
                stage(aslab + dy * ROWB, ym + dy - 1, t);
            }
        }
    } else {
        for (int tau = w4; tau < 24; tau += 4) {
            int r = tau >> 2, t = tau & 3;
            int y = lo - 1 + r;
            stage(ring + ((y + 1) % NRING) * ROWB, y, t);
        }
    }

    const int xn = (nh << 5) + l31;   // lane's n-column
    const int xm = (mt << 5) + l31;   // lane's m-position (A-side)
    const int soL = h * STRIPE;       // stripe g = h     (qq=0 half)
    const int soH = (2 + h) * STRIPE; // stripe g = 2 + h (qq=1 half)

    // 32B MX operand: stripe pair {h, 2+h} at pixel offset -> v8i32
    auto ld32 = [&](const char* slab, int off) -> int8v {
        uint4v r0 = *(const uint4v*)(slab + soL + off);
        uint4v r1 = *(const uint4v*)(slab + soH + off);
        int8v a;
        a[0] = r0[0]; a[1] = r0[1]; a[2] = r0[2]; a[3] = r0[3];
        a[4] = r1[0]; a[5] = r1[1]; a[6] = r1[2]; a[7] = r1[3];
        return a;
    };

    __syncthreads();   // prologue DMAs drained (incl. aslab)

    // ---- A-fragments hoisted to registers: loop-invariant, 9 x int8v ----
    int8v Areg0[3], Areg1[3], Areg2[3];   // [dyi] x [dx], statically unrolled
    #pragma unroll
    for (int dx = 0; dx < 3; ++dx) {
        const int oa = (xm + dx) * 16;
        Areg0[dx] = ld32(aslab + 0 * ROWB, oa);
        Areg1[dx] = ld32(aslab + 1 * ROWB, oa);
        Areg2[dx] = ld32(aslab + 2 * ROWB, oa);
    }

    float Mref[16];
    #pragma unroll
    for (int r = 0; r < 16; ++r)
        Mref[r] = mref_lds[(mt << 5) + (r & 3) + ((r >> 2) << 3) + (h << 2)];

    // 8 barrier periods; each = 4-row prefetch + TWO 2-gen sub-superphases.
    #pragma unroll 1
    for (int p = 0; p < 8; ++p) {
        const int y0 = lo + (p << 2);

        // async prefetch rows y0+5..y0+8 -> slots (y0+6..y0+9)%10, disjoint
        // from this period's working slots (y0..y0+5)%10. 16 tasks over 4
        // waves: wave w4 stages stripe w4 of each of the 4 rows.
        if (p < 7) {
            #pragma unroll
            for (int k = 0; k < 4; ++k) {
                int y = y0 + 5 + k;
                stage(ring + ((y + 1) % NRING) * ROWB, y, w4);
            }
        }

        #pragma unroll
        for (int s = 0; s < 2; ++s) {
            const int yb = y0 + (s << 1);   // gens yb, yb+1

            f32x16 acc0, acc1;
            #pragma unroll
            for (int r = 0; r < 16; ++r) { acc0[r] = 0.f; acc1[r] = 0.f; }

            const char* rb[4];
            #pragma unroll
            for (int j2 = 0; j2 < 4; ++j2)
                rb[j2] = ring + ((yb + j2) % NRING) * ROWB;   // row yb-1+j2

            #pragma unroll
            for (int dx = 0; dx < 3; ++dx) {
                const int ob = (xn + dx) * 16;
                int8v Bb0 = ld32(rb[0], ob);
                int8v Bb1 = ld32(rb[1], ob);
                int8v Bb2 = ld32(rb[2], ob);
                int8v Bb3 = ld32(rb[3], ob);
                acc0 = MXMFMA(Areg0[dx], Bb0, acc0);
                acc0 = MXMFMA(Areg1[dx], Bb1, acc0);
                acc0 = MXMFMA(Areg2[dx], Bb2, acc0);
                acc1 = MXMFMA(Areg0[dx], Bb1, acc1);
                acc1 = MXMFMA(Areg1[dx], Bb2, acc1);
                acc1 = MXMFMA(Areg2[dx], Bb3, acc1);
            }

            // fixed-reference softmax: guard-gated LDS accumulation
            #pragma unroll
            for (int j = 0; j < 2; ++j) {
                const f32x16& ac = (j == 0) ? acc0 : acc1;
                float v[16]; int upd = 0;
                #pragma unroll
                for (int r = 0; r < 16; ++r) {
                    v[r] = fmaf(ac[r], SCALE2, -Mref[r]);
                    upd |= (v[r] > -30.0f) ? 1 : 0;
                }
                if (__any(upd)) {
                    const int yn = yb + j;
                    float av = aab[yn * W_ + xn];
                    float bv = bab[yn * W_ + xn];
                    #pragma unroll
                    for (int r = 0; r < 16; ++r) {
                        float pp  = exp2f(fminf(v[r], 80.0f));
                        float w0c = pp * av;
                        float w1c = pp * bv;
                        #pragma unroll
                        for (int off = 16; off >= 1; off >>= 1) {
                            pp  += __shfl_xor(pp,  off);
                            w0c += __shfl_xor(w0c, off);
                            w1c += __shfl_xor(w1c, off);
                        }
                        if (l31 == 0) {
                            int m = (mt << 5) + (r & 3) + ((r >> 2) << 3) + (h << 2);
                            float* st = &state[zh][nh][m][0];
                            st[0] += pp; st[1] += w0c; st[2] += w1c;
                        }
                    }
                }
            }
        }
        __syncthreads();   // period DMAs drained; slots rotate; state visible
    }

    // final: sum the 4 partial states, write output directly
    if (tid < 64) {
        float Ssum = 0.f, w0 = 0.f, w1 = 0.f;
        #pragma unroll
        for (int z2 = 0; z2 < 2; ++z2)
            #pragma unroll
            for (int n2i = 0; n2i < 2; ++n2i) {
                Ssum += state[z2][n2i][tid][0];
                w0   += state[z2][n2i][tid][1];
                w1   += state[z2][n2i][tid][2];
            }
        float inv = 1.0f / Ssum;
        out[(((size_t)b * 2 + 0) * H_ + ym) * W_ + tid] = w0 * inv;
        out[(((size_t)b * 2 + 1) * H_ + ym) * W_ + tid] = w1 * inv;
    }
}

extern "C" void kernel_launch(void* const* d_in, const int* in_sizes, int n_in,
                              void* d_out, int out_size, void* d_ws, size_t ws_size,
                              hipStream_t stream) {
    const float* xlab = (const float*)d_in[0];
    const float* feat = (const float*)d_in[1];
    float* out = (float*)d_out;
    unsigned char* tf = (unsigned char*)d_ws;                          // 1 MB
    float* n2   = (float*)((char*)d_ws + (size_t)1024 * 1024);         // 64 KB

    dim3 gridT(H_, B_);
    feat_to_fp8<<<gridT, 256, 0, stream>>>(feat, tf, n2);
    dim3 gridM(H_, B_);
    nlwa_fp8<<<gridM, 512, 0, stream>>>(xlab, tf, n2, out);
}